// Round 5
// baseline (320.202 us; speedup 1.0000x reference)
//
#include <hip/hip_runtime.h>

#define NROWS   262144
#define NCODES  1024
#define DIM     64
#define NTILES  64       // 16-code MFMA tiles covering 1024 codes
#define TSTRIDE 2304     // bytes per tile: 2048 fragment + 64 hc + 192 pad
#define PADT    4        // prefetch overrun pad (tiles 64..67 read, never used)

typedef _Float16 half8 __attribute__((ext_vector_type(8)));
typedef __attribute__((ext_vector_type(4))) float f32x4;

#define MFMA16(acc, a, b) acc = __builtin_amdgcn_mfma_f32_16x16x32_f16(a, b, acc, 0, 0, 0)

// ---------------------------------------------------------------------------
// Prep: arithmetic bit-identical to the validated version (sequential chain
// sums, true residual, RNE fp16). Layout: fp16 codebook in MFMA B-fragment
// order (validated in R3), tile stride 2304 with the NEGATED half-square
// table interleaved at tile_base+2048 (float per code-in-tile) so vq_main
// prefetches it in the same global stream (no LDS at all).
// E^2 is plain-stored per prep-wave into eslots[16] (no atomicMax -> no
// memset needed); main takes the max of the 16 slots (same value as before).
// ---------------------------------------------------------------------------
__global__ __launch_bounds__(256) void vq_prep(const float* __restrict__ cb,
                                               float* __restrict__ hcsq,
                                               char* __restrict__ stream,
                                               float* __restrict__ eslots) {
    const int k = blockIdx.x * 256 + threadIdx.x;   // 0..1023
    const float4* row = (const float4*)(cb + (size_t)k * DIM);
    char* base = stream + (size_t)(k >> 4) * TSTRIDE + (size_t)(k & 15) * 16;
    float s = 0.f, r2 = 0.f;
#pragma unroll
    for (int i = 0; i < 8; ++i) {   // chunk i: halves i*8..i*8+7
        float4 a = row[2 * i], b = row[2 * i + 1];
        float v[8] = {a.x, a.y, a.z, a.w, b.x, b.y, b.z, b.w};
        union { half8 f; _Float16 e[8]; } uh;
#pragma unroll
        for (int j = 0; j < 8; ++j) {
            float c = v[j];
            s += c * c;                    // sequential chain (matches r4/r1)
            _Float16 h = (_Float16)c;      // RNE
            uh.e[j] = h;
            float d = c - (float)h;        // true residual
            r2 += d * d;
        }
        // chunk i -> j = i>>2 slot, q-position = i&3 (validated R3 layout)
        *(half8*)(base + ((i >> 2) << 10) + ((i & 3) << 8)) = uh.f;
    }
    hcsq[k] = 0.5f * s;   // kept for the exact inline rescue
    *(float*)(stream + (size_t)(k >> 4) * TSTRIDE + 2048 + (size_t)(k & 15) * 4) = -0.5f * s;
    float w = r2;
#pragma unroll
    for (int off = 1; off < 64; off <<= 1) w = fmaxf(w, __shfl_xor(w, off));
    if ((threadIdx.x & 63) == 0)
        eslots[blockIdx.x * 4 + (threadIdx.x >> 6)] = w;   // plain store
}

// ---------------------------------------------------------------------------
// Main. Same score math / margins as the validated kernels (fp16 hi+lo
// 2-term, -hc folded into acc init, fused top-2, margin 2(||x||E+1e-3)).
// ZERO LDS, ZERO barriers. B-fragments AND -hc stream global->VGPR from the
// L2-resident tile stream via a 4-tile rotating register pipeline. Flagged
// near-tie rows are re-solved INLINE with the verbatim validated exact-fp32
// rescue arithmetic.
// R4-BUGFIX: rowmask bits are set by ALL lanes of the 16-lane merge group
// (flg is group-uniform), so the xor-16/32 OR-reduce yields the complete
// wave mask in every lane and the rescue loop runs wave-uniform. The R4
// `m==0 &&` filter left 60/64 lanes with mask=0 -> divergent rescue ->
// garbage shuffles + partial row writes (absmax 4.48).
// ---------------------------------------------------------------------------
#define SELECT(aa, ab, tl)                                                        \
    {                                                                             \
        const int _tl = (tl);                                                     \
        _Pragma("unroll")                                                         \
        for (int r = 0; r < 4; ++r) {                                             \
            float s0 = (aa)[r];                                                   \
            bool g0 = s0 > best[0][r];                                            \
            second[0][r] = __builtin_amdgcn_fmed3f(s0, best[0][r], second[0][r]); \
            best[0][r] = g0 ? s0 : best[0][r];                                    \
            btile[0][r] = g0 ? _tl : btile[0][r];                                 \
            float s1 = (ab)[r];                                                   \
            bool g1 = s1 > best[1][r];                                            \
            second[1][r] = __builtin_amdgcn_fmed3f(s1, best[1][r], second[1][r]); \
            best[1][r] = g1 ? s1 : best[1][r];                                    \
            btile[1][r] = g1 ? _tl : btile[1][r];                                 \
        }                                                                         \
    }

// One tile: select the OTHER acc pair (lag-1), init this pair to -hc (already
// in register nh, prefetched 4 tiles ahead), 8 MFMA from fragment regs, then
// refill fragments + nh with the tile 4 ahead.
#define PHASE(fA, fB, nh, a0, a1, o0, o1, TT)                 \
    {                                                         \
        SELECT(o0, o1, (TT) - 1);                             \
        a0 = (f32x4){nh, nh, nh, nh};                         \
        a1 = a0;                                              \
        MFMA16(a0, xh[0][0], fA); MFMA16(a1, xh[1][0], fA);   \
        MFMA16(a0, xh[0][1], fB); MFMA16(a1, xh[1][1], fB);   \
        MFMA16(a0, xl[0][0], fA); MFMA16(a1, xl[1][0], fA);   \
        MFMA16(a0, xl[0][1], fB); MFMA16(a1, xl[1][1], fB);   \
        fA = *(const half8*)(gpre);                           \
        fB = *(const half8*)(gpre + 1024);                    \
        nh = *(const float*)(gpre + hdelta);                  \
        gpre += TSTRIDE;                                      \
    }

__global__ __launch_bounds__(256, 4) void vq_main(const float* __restrict__ inputs,
                                                  const float* __restrict__ cb,
                                                  const float* __restrict__ hcsq,
                                                  const char* __restrict__ stream,
                                                  const float* __restrict__ eslots,
                                                  float* __restrict__ out) {
    const int tid = threadIdx.x;
    const int lane = tid & 63;
    const int wave = tid >> 6;
    const int m = lane & 15;   // A row-in-tile / B code-in-tile / D col
    const int q = lane >> 4;   // k-quad
    const size_t rowbase = (size_t)blockIdx.x * 128 + (size_t)wave * 32;

    float e2 = 0.f;
#pragma unroll
    for (int i = 0; i < 16; ++i) e2 = fmaxf(e2, eslots[i]);
    const float E = sqrtf(e2) * 1.001f;

    // A fragments (fp16 hi+lo of x) + exact row sum-of-squares for the margin.
    half8 xh[2][2], xl[2][2];
    float xsq[2];
#pragma unroll
    for (int t = 0; t < 2; ++t) {
        const float* px = inputs + (rowbase + t * 16 + m) * DIM;
        float acc = 0.f;
#pragma unroll
        for (int s = 0; s < 2; ++s) {
            const float4* p = (const float4*)(px + q * 8 + s * 32);
            float4 v0 = p[0], v1 = p[1];
            float v[8] = {v0.x, v0.y, v0.z, v0.w, v1.x, v1.y, v1.z, v1.w};
            union { half8 f; _Float16 e[8]; } uh, ul;
#pragma unroll
            for (int j = 0; j < 8; ++j) {
                acc += v[j] * v[j];
                _Float16 h = (_Float16)v[j];
                uh.e[j] = h;
                ul.e[j] = (_Float16)(v[j] - (float)h);
            }
            xh[t][s] = uh.f;
            xl[t][s] = ul.f;
        }
        acc += __shfl_xor(acc, 16);   // reduce across k-quads (same m)
        acc += __shfl_xor(acc, 32);
        xsq[t] = acc;
    }

    float best[2][4], second[2][4];
    int btile[2][4];
#pragma unroll
    for (int t = 0; t < 2; ++t)
#pragma unroll
        for (int r = 0; r < 4; ++r) {
            best[t][r] = -INFINITY;
            second[t][r] = -INFINITY;
            btile[t][r] = 0;
        }

    // 4-tile rotating register prefetch over the tile stream (frags + nh).
    const char* gL = stream + (size_t)lane * 16;
    const int hdelta = 2048 + m * 4 - lane * 16;   // nh addr rel. to frag ptr
    half8 f0a = *(const half8*)(gL);
    half8 f0b = *(const half8*)(gL + 1024);
    float nh0 = *(const float*)(gL + hdelta);
    half8 f1a = *(const half8*)(gL + TSTRIDE);
    half8 f1b = *(const half8*)(gL + TSTRIDE + 1024);
    float nh1 = *(const float*)(gL + TSTRIDE + hdelta);
    half8 f2a = *(const half8*)(gL + 2 * TSTRIDE);
    half8 f2b = *(const half8*)(gL + 2 * TSTRIDE + 1024);
    float nh2 = *(const float*)(gL + 2 * TSTRIDE + hdelta);
    half8 f3a = *(const half8*)(gL + 3 * TSTRIDE);
    half8 f3b = *(const half8*)(gL + 3 * TSTRIDE + 1024);
    float nh3 = *(const float*)(gL + 3 * TSTRIDE + hdelta);
    const char* gpre = gL + 4 * TSTRIDE;

    // Lag-1 select pipeline; dummy -INF makes the first select a no-op.
    f32x4 accA0, accA1, accB0, accB1;
    accB0 = (f32x4){-INFINITY, -INFINITY, -INFINITY, -INFINITY};
    accB1 = accB0;

    for (int it = 0; it < 16; ++it) {
        const int T = it * 4;
        PHASE(f0a, f0b, nh0, accA0, accA1, accB0, accB1, T + 0);
        PHASE(f1a, f1b, nh1, accB0, accB1, accA0, accA1, T + 1);
        PHASE(f2a, f2b, nh2, accA0, accA1, accB0, accB1, T + 2);
        PHASE(f3a, f3b, nh3, accB0, accB1, accA0, accA1, T + 3);
    }
    SELECT(accB0, accB1, NTILES - 1);   // drain last pending tile

    // Cross-lane top-2 merge (16-lane groups), min-index tie-break; gather,
    // write non-flagged rows, collect flagged rows into a per-wave bitmask.
    unsigned rowmask = 0;
#pragma unroll
    for (int t = 0; t < 2; ++t)
#pragma unroll
        for (int r = 0; r < 4; ++r) {
            float b = best[t][r], sc = second[t][r];
            int bi = btile[t][r] * 16 + m;   // reconstruct code index
#pragma unroll
            for (int off = 1; off < 16; off <<= 1) {
                float ob = __shfl_xor(b, off);
                float os = __shfl_xor(sc, off);
                int oi = __shfl_xor(bi, off);
                sc = fmaxf(fmaxf(sc, os), fminf(b, ob));
                if (ob > b || (ob == b && oi < bi)) { b = ob; bi = oi; }
            }
            size_t row = rowbase + t * 16 + q * 4 + r;
            float xs = __shfl(xsq[t], (lane & 48) | (q * 4 + r));
            float marg = 2.0f * (sqrtf(xs) * E + 1e-3f);
            bool flg = (b - sc) < marg;   // group-uniform (b, sc, xs uniform)
            if (!flg) {
                const float4* src = (const float4*)(cb + (size_t)bi * DIM);
                ((float4*)(out + row * DIM))[m] = src[m];
            } else {
                rowmask |= 1u << (t * 16 + q * 4 + r);   // ALL lanes (bugfix)
            }
        }

    // Inline exact rescue (verbatim validated fp32 arithmetic) for flagged
    // rows, whole-wave per row. Lane l holds bits for its own q-group; the
    // xor-16/32 OR combines lanes {l, l^16, l^32, l^48} = all 4 q's -> every
    // lane ends with the complete wave mask -> wave-uniform loop.
    rowmask |= __shfl_xor(rowmask, 16);
    rowmask |= __shfl_xor(rowmask, 32);
    while (rowmask) {
        const int rid = __builtin_ctz(rowmask);
        rowmask &= rowmask - 1;
        const size_t row = rowbase + rid;
        const int sub = lane & 15;  // dim quad
        const int g = lane >> 4;    // code within 4-group
        float4 xv = ((const float4*)(inputs + row * DIM))[sub];
        float rb = -INFINITY;
        int rbi = 0;
#pragma unroll 8
        for (int c4 = 0; c4 < NCODES / 4; ++c4) {
            int c = c4 * 4 + g;
            float4 cv = ((const float4*)(cb + (size_t)c * DIM))[sub];
            float p = xv.x * cv.x + xv.y * cv.y + xv.z * cv.z + xv.w * cv.w;
            p += __shfl_xor(p, 1);
            p += __shfl_xor(p, 2);
            p += __shfl_xor(p, 4);
            p += __shfl_xor(p, 8);
            float s = p - hcsq[c];
            if (s > rb) { rb = s; rbi = c; }
        }
#pragma unroll
        for (int off = 16; off < 64; off <<= 1) {
            float ob = __shfl_xor(rb, off);
            int oi = __shfl_xor(rbi, off);
            if (ob > rb || (ob == rb && oi < rbi)) { rb = ob; rbi = oi; }
        }
        out[row * DIM + lane] = cb[(size_t)rbi * DIM + lane];
    }
}

extern "C" void kernel_launch(void* const* d_in, const int* in_sizes, int n_in,
                              void* d_out, int out_size, void* d_ws, size_t ws_size,
                              hipStream_t stream_) {
    const float* inputs = (const float*)d_in[0];    // [262144, 64] fp32
    const float* cb = (const float*)d_in[1];        // [1024, 64] fp32
    float* out = (float*)d_out;

    // ws: hcsq f32[1024] | tile stream [68 x 2304 B] | eslots f32[16]
    char* ws = (char*)d_ws;
    float* hcsq = (float*)ws;                                       //   4 KiB
    char* strm = ws + 4096;                                         // 153 KiB
    float* eslots = (float*)(ws + 4096 + (NTILES + PADT) * TSTRIDE);

    vq_prep<<<4, 256, 0, stream_>>>(cb, hcsq, strm, eslots);
    vq_main<<<NROWS / 128, 256, 0, stream_>>>(inputs, cb, hcsq, strm, eslots, out);
}